// Round 14
// baseline (72.549 us; speedup 1.0000x reference)
//
#include <hip/hip_runtime.h>
#include <math.h>

#define D_MODEL 2048
#define NUM_EXP 64
#define TOKB    32
#define NGRAN   64              // granules of 32 k-floats
#define NBUF    4
#define BUFSZ   12288           // per-buffer: 4 KB x (fp32) + 8 KB W (f16 hi/lo)

typedef _Float16 f16x8 __attribute__((ext_vector_type(8)));
typedef float    f32x4 __attribute__((ext_vector_type(4)));

__device__ __forceinline__ void gload16(const void* g, void* l) {
    __builtin_amdgcn_global_load_lds(
        (const __attribute__((address_space(1))) unsigned int*)g,
        (__attribute__((address_space(3))) unsigned int*)l, 16, 0, 0);
}

// ---------------------------------------------------------------------------
// k0: W[64][2048] fp32 -> fragment-linear f16 hi/lo (W = wh + wl*2^-12, wl
// scaled 4096; exact split). Frag (kc, mf): lane l holds
// A[m = mf*16 + (l&15)][k = kc*32 + (l>>4)*8 + j], flat at whf[(kc*4+mf)*64+l].
// ---------------------------------------------------------------------------
__global__ __launch_bounds__(256)
void k0_convw(const float* __restrict__ W, f16x8* __restrict__ whf,
              f16x8* __restrict__ wlf) {
    const int t    = blockIdx.x * 256 + threadIdx.x;
    const int lane = t & 63;
    const int mf   = (t >> 6) & 3;
    const int kc   = t >> 8;
    const int m    = mf * 16 + (lane & 15);
    const int k0   = kc * 32 + ((lane >> 4) << 3);
    const float* src = W + (size_t)m * D_MODEL + k0;
    f16x8 h, l;
#pragma unroll
    for (int j = 0; j < 8; ++j) {
        float v = src[j];
        _Float16 hh = (_Float16)v;
        h[j] = hh;
        l[j] = (_Float16)((v - (float)hh) * 4096.f);
    }
    whf[t] = h;
    wlf[t] = l;
}

// ---------------------------------------------------------------------------
// k1: pure-DMA pipelined fused router. ZERO global reg-loads in the K-loop --
// all staging via global_load_lds (no dest VGPRs -> queue depth immune to the
// register allocator, the failure mode of R5/R6/R9/R13).
// Block = 256 thr (4 waves) = 32 tok x 64 exp x full K. Wave w = expert
// 16-group mf=w, both 16-token halves; acc = 2x f32x4 pair (full-K, no split).
// Per granule (32 k): wave issues exactly 3 DMA (1 x-instr: rows w*8..w*8+7;
// 2 W-instr: its own frag hi+lo, fragment-linear source, linear LDS dest).
// NBUF=4, issue depth 2, steady s_waitcnt vmcnt(6) (retires granule g, keeps
// g+1,g+2 = 6 in flight), raw s_barrier (+asm memory fences). Buffer safety:
// I(g+2) writes (g+2)&3; concurrent readers only at g,g-1 -> distinct.
// x content pre-swizzled at the SOURCE (col4 ^= row&7, linear dest; reader
// XORs the same) -> ds_read_b128 2-way conflicts (free). W slots staged and
// read by the same wave (conflict-free linear b128).
// cvt fp32->f16 hi/lo once per element per wave (exact split:
// logits = xh*wh + 2^-12(xh*wl + xl*wh), low terms scaled 2^12).
// Epilogue: ep tile aliased onto the dead arena; per-wave softmax + top-2
// (lax.top_k tie rule: lower index wins) + per-block expert partials.
// Grid: N/32 = 512 blocks; LDS ~50 KB -> 2 blocks/CU, 2 waves/SIMD.
// ---------------------------------------------------------------------------
__global__ __launch_bounds__(256, 2)
void k1_fused(const float* __restrict__ x, const f16x8* __restrict__ whf,
              const f16x8* __restrict__ wlf, float* __restrict__ out,
              float* __restrict__ p_part, float* __restrict__ f_part, int N) {
    const int tid  = threadIdx.x;
    const int lane = tid & 63;
    const int w    = tid >> 6;          // wave 0..3 == expert 16-group (mf)
    const int tok0 = blockIdx.x * TOKB;

    __shared__ __align__(16) char arena[NBUF * BUFSZ];   // 48 KB
    __shared__ float p_red[4][64], f_red[4][64];

    // --- DMA source addresses ---------------------------------------------
    // x instr (1/wave): dest = buf + w*1024 (linear); lane -> row w*8+(l>>3),
    // piece l&7. Source col4 = (l&7) ^ (row&7)  (swizzle involution).
    const int xrow = w * 8 + (lane >> 3);
    const int xc4  = (lane & 7) ^ (xrow & 7);
    const float* xsrc = x + (size_t)(tok0 + xrow) * D_MODEL + xc4 * 4;
    // W instr (2/wave): wave w stages ITS OWN frag (mf=w) hi+lo.
    const f16x8* whsrc = whf + (size_t)w * 64 + lane;    // + g*256
    const f16x8* wlsrc = wlf + (size_t)w * 64 + lane;

    auto ISSUE = [&](int g) {
        char* base = arena + (size_t)(g & (NBUF - 1)) * BUFSZ;
        gload16(xsrc + (size_t)g * 32, base + w * 1024);
        gload16(whsrc + (size_t)g * 256, base + 4096 + (2 * w) * 1024);
        gload16(wlsrc + (size_t)g * 256, base + 4096 + (2 * w + 1) * 1024);
    };

    f32x4 acc1[2], acc2[2];
#pragma unroll
    for (int t2 = 0; t2 < 2; ++t2) {
        acc1[t2] = f32x4{0.f, 0.f, 0.f, 0.f};
        acc2[t2] = f32x4{0.f, 0.f, 0.f, 0.f};
    }

    const int ft = lane & 15;
    const int fs = lane >> 4;

    auto COMPUTE = [&](int g) {
        const char* xb = arena + (size_t)(g & (NBUF - 1)) * BUFSZ;
        const f16x8 wh = *(const f16x8*)(xb + 4096 + (2 * w) * 1024 + lane * 16);
        const f16x8 wl = *(const f16x8*)(xb + 4096 + (2 * w) * 1024 + 1024 + lane * 16);
        __builtin_amdgcn_s_setprio(1);
#pragma unroll
        for (int t2 = 0; t2 < 2; ++t2) {
            const int r = t2 * 16 + ft;
            const f32x4 u0 = *(const f32x4*)(xb + r * 128 + (((2 * fs + 0) ^ (r & 7)) << 4));
            const f32x4 u1 = *(const f32x4*)(xb + r * 128 + (((2 * fs + 1) ^ (r & 7)) << 4));
            f16x8 xh, xl;
#pragma unroll
            for (int j = 0; j < 4; ++j) {
                _Float16 h = (_Float16)u0[j];
                xh[j] = h;
                xl[j] = (_Float16)((u0[j] - (float)h) * 4096.f);
            }
#pragma unroll
            for (int j = 0; j < 4; ++j) {
                _Float16 h = (_Float16)u1[j];
                xh[4 + j] = h;
                xl[4 + j] = (_Float16)((u1[j] - (float)h) * 4096.f);
            }
            acc1[t2] = __builtin_amdgcn_mfma_f32_16x16x32_f16(wh, xh, acc1[t2], 0, 0, 0);
            acc2[t2] = __builtin_amdgcn_mfma_f32_16x16x32_f16(wh, xl, acc2[t2], 0, 0, 0);
            acc2[t2] = __builtin_amdgcn_mfma_f32_16x16x32_f16(wl, xh, acc2[t2], 0, 0, 0);
        }
        __builtin_amdgcn_s_setprio(0);
    };

    // --- prologue + steady loop (vmcnt never 0) + peeled tail --------------
    ISSUE(0);
    ISSUE(1);
    for (int g = 0; g < NGRAN - 2; ++g) {
        ISSUE(g + 2);
        asm volatile("s_waitcnt vmcnt(6)" ::: "memory");
        __builtin_amdgcn_s_barrier();
        asm volatile("" ::: "memory");
        COMPUTE(g);
    }
    asm volatile("s_waitcnt vmcnt(3)" ::: "memory");
    __builtin_amdgcn_s_barrier();
    asm volatile("" ::: "memory");
    COMPUTE(NGRAN - 2);
    asm volatile("s_waitcnt vmcnt(0)" ::: "memory");
    __builtin_amdgcn_s_barrier();
    asm volatile("" ::: "memory");
    COMPUTE(NGRAN - 1);
    __syncthreads();

    // --- epilogue: ep tile aliased onto the dead arena ---------------------
    // C layout: col = lane&15 = token, row = fs*4 + p = expert (in w*16).
    float (*ep)[68] = (float(*)[68])arena;           // 32 x 68 x 4 = 8704 B
#pragma unroll
    for (int t2 = 0; t2 < 2; ++t2) {
        f32x4 o = acc1[t2] + acc2[t2] * (1.f / 4096.f);
        *(f32x4*)&ep[t2 * 16 + ft][w * 16 + fs * 4] = o;
    }
    __syncthreads();

    // --- softmax + top-2, 8 tokens per wave (lane == expert) ---------------
    float pacc = 0.f, facc = 0.f;
#pragma unroll
    for (int i = 0; i < 8; ++i) {
        const int tl = w * 8 + i;
        float logit = ep[tl][lane];

        float m = logit;
        for (int off = 32; off; off >>= 1) m = fmaxf(m, __shfl_xor(m, off));
        float p = __expf(logit - m);
        float S = p;
        for (int off = 32; off; off >>= 1) S += __shfl_xor(S, off);
        float prob = p / S;

        float bv = logit; int bi = lane;
        for (int off = 32; off; off >>= 1) {
            float ov = __shfl_xor(bv, off);
            int   oi = __shfl_xor(bi, off);
            if (ov > bv || (ov == bv && oi < bi)) { bv = ov; bi = oi; }
        }
        float cv = (lane == bi) ? -INFINITY : logit;
        int   ci = lane;
        for (int off = 32; off; off >>= 1) {
            float ov = __shfl_xor(cv, off);
            int   oi = __shfl_xor(ci, off);
            if (ov > cv || (ov == cv && oi < ci)) { cv = ov; ci = oi; }
        }

        if (lane == 0) {
            const int gt = tok0 + tl;
            float w0 = 1.f / (1.f + __expf(cv - bv));
            out[(size_t)gt * 2]     = w0;
            out[(size_t)gt * 2 + 1] = 1.f - w0;
            out[(size_t)2 * N + gt * 2]     = (float)bi;
            out[(size_t)2 * N + gt * 2 + 1] = (float)ci;
        }

        pacc += prob;
        facc += (lane == bi ? 1.f : 0.f) + (lane == ci ? 1.f : 0.f);
    }

    p_red[w][lane] = pacc;
    f_red[w][lane] = facc;
    __syncthreads();
    if (w == 0) {
        float sp = p_red[0][lane] + p_red[1][lane] + p_red[2][lane] + p_red[3][lane];
        float sf = f_red[0][lane] + f_red[1][lane] + f_red[2][lane] + f_red[3][lane];
        p_part[(size_t)blockIdx.x * NUM_EXP + lane] = sp;
        f_part[(size_t)blockIdx.x * NUM_EXP + lane] = sf;
    }
}

// ---------------------------------------------------------------------------
// k3: deterministic aux-loss reduction over 512 per-block partials.
// aux = E * sum_i (f_sum_i / N) * (p_sum_i / N)
// ---------------------------------------------------------------------------
__global__ __launch_bounds__(1024)
void k3_aux(const float* __restrict__ p_part, const float* __restrict__ f_part,
            float* __restrict__ out, int N, int B2) {
    const int lane = threadIdx.x & 63;
    const int wid  = threadIdx.x >> 6;    // 0..15
    float sp = 0.f, sf = 0.f;
    for (int b = wid; b < B2; b += 16) {
        sp += p_part[(size_t)b * NUM_EXP + lane];
        sf += f_part[(size_t)b * NUM_EXP + lane];
    }
    __shared__ float lsp[16][64];
    __shared__ float lsf[16][64];
    lsp[wid][lane] = sp;
    lsf[wid][lane] = sf;
    __syncthreads();
    if (wid == 0) {
        float tsp = 0.f, tsf = 0.f;
#pragma unroll
        for (int q = 0; q < 16; ++q) { tsp += lsp[q][lane]; tsf += lsf[q][lane]; }
        float v = tsp * tsf;
        for (int off = 32; off; off >>= 1) v += __shfl_xor(v, off);
        if (lane == 0)
            out[(size_t)4 * N] = (float)NUM_EXP * v / ((float)N * (float)N);
    }
}

extern "C" void kernel_launch(void* const* d_in, const int* in_sizes, int n_in,
                              void* d_out, int out_size, void* d_ws, size_t ws_size,
                              hipStream_t stream) {
    const float* x = (const float*)d_in[0];
    const float* W = (const float*)d_in[1];
    float* out = (float*)d_out;

    const int N  = in_sizes[0] / D_MODEL;   // 16384
    const int B1 = N / TOKB;                // 512 blocks

    // ws: [whf 256KB][wlf 256KB][p_part 128KB][f_part 128KB]
    f16x8* whf = (f16x8*)d_ws;
    f16x8* wlf = whf + 16384;
    float* p_part = (float*)(wlf + 16384);
    float* f_part = p_part + (size_t)B1 * NUM_EXP;

    k0_convw<<<64, 256, 0, stream>>>(W, whf, wlf);
    k1_fused<<<B1, 256, 0, stream>>>(x, whf, wlf, out, p_part, f_part, N);
    k3_aux<<<1, 1024, 0, stream>>>(p_part, f_part, out, N, B1);
}